// Round 13
// baseline (360.450 us; speedup 1.0000x reference)
//
#include <hip/hip_runtime.h>

// BoxMultiHeadedAttention: B=4, S=1024, D=1024, H=16, DK=64.
// R17: post-mortem R10 — 3-buffer regressed (occ 27%), maskflags won (kept).
// This round: gemm_dma back to 2-buffer 64KB, BK=64, with T2 XOR bank-swizzle
// (linear LDS dest + inverse-swizzled global source lane cols + swizzled
// ds_read). 8-way conflict -> 2-way (free); barriers halved.
// (R19 resubmit — R17/R18 never ran: GPU acquisition timeouts.)

typedef unsigned short u16;
typedef __bf16 bf16x8 __attribute__((ext_vector_type(8)));
typedef float f32x4 __attribute__((ext_vector_type(4)));

#define DEV static __device__ __forceinline__

DEV u16 f2bf(float x) {
  union { __bf16 h; u16 u; } c;
  c.h = (__bf16)x;
  return c.u;
}
DEV float bf2f(u16 h) { return __uint_as_float(((unsigned)h) << 16); }

DEV bf16x8 cvt8(float4 a, float4 b) {
  bf16x8 v;
  v[0] = (__bf16)a.x; v[1] = (__bf16)a.y; v[2] = (__bf16)a.z; v[3] = (__bf16)a.w;
  v[4] = (__bf16)b.x; v[5] = (__bf16)b.y; v[6] = (__bf16)b.z; v[7] = (__bf16)b.w;
  return v;
}

DEV void gload_lds16(const void* g, void* l) {
  __builtin_amdgcn_global_load_lds(
      (const __attribute__((address_space(1))) void*)g,
      (__attribute__((address_space(3))) void*)l, 16, 0, 0);
}

// ---------------------------------------------------------------------------
// fp32 -> bf16 pre-conversion (12 segments: 5 acts, 7 weights)
// ---------------------------------------------------------------------------
struct CvtArgs {
  const float* src[12];
  u16* dst[12];
  int n8[12];  // elem count / 8
};

__global__ __launch_bounds__(256) void cvt_kernel(CvtArgs C) {
  const int stride = gridDim.x * blockDim.x;
#pragma unroll 1
  for (int s = 0; s < 12; ++s) {
    const float4* src = (const float4*)C.src[s];
    u16* dst = C.dst[s];
    const int n8 = C.n8[s];
    for (int i = blockIdx.x * blockDim.x + threadIdx.x; i < n8; i += stride) {
      const float4 a = src[i * 2];
      const float4 b = src[i * 2 + 1];
      *(bf16x8*)(void*)(dst + (size_t)i * 8) = cvt8(a, b);
    }
  }
}

// ---------------------------------------------------------------------------
// mask all-nonzero flags per (b, qtile128, ktile64): 4 x 8 x 16 = 512 flags.
// Verified R10 (354us pass).
// ---------------------------------------------------------------------------
__global__ __launch_bounds__(256) void maskflags_kernel(const int* __restrict__ mask,
                                                        int* __restrict__ flags) {
  const int bid = blockIdx.x;  // b*128 + qt*16 + kt
  const int kt = bid & 15, qt = (bid >> 4) & 7, b = bid >> 7;
  const int tid = threadIdx.x;
  __shared__ int f;
  if (tid == 0) f = 1;
  __syncthreads();
  int ok = 1;
  const int c = tid & 15;
  const int r0 = tid >> 4;
#pragma unroll
  for (int p = 0; p < 8; ++p) {
    const int row = qt * 128 + p * 16 + r0;
    const int4 m4 = *(const int4*)(const void*)(
        mask + ((size_t)b * 1024 + row) * 1024 + kt * 64 + c * 4);
    if (!(m4.x && m4.y && m4.z && m4.w)) ok = 0;
  }
  if (!ok) atomicAnd(&f, 0);
  __syncthreads();
  if (tid == 0) flags[bid] = f;
}

// ---------------------------------------------------------------------------
// DMA GEMM, BK=64, bank-swizzled. 128x128 tile, 4 waves 2x2, 2-buffer 64KB.
// Swizzle (involution, both sides): LDS[row][c] = G[row][c ^ ((row&7)*8)].
// DMA side: lane l of instr i writes LDS row (w*4+i)*8 + (l>>3), col (l&7)*8;
//   row&7 == l>>3, so lane loads global col ((l&7)^(l>>3))*8.  [m173/m201]
// Read side: fragment (row R, col (kk*4+gl)*8) -> LDS col ((kk*4+gl)^(R&7))*8,
//   R&7 == cl&7. 16 cl-lanes hit 8 slot-groups x 2 = 2-way (free, m136).
// ---------------------------------------------------------------------------
struct ArgsD {
  const u16* act[5];   // bf16 [4096][1024]
  const u16* W[7];     // bf16 [N][K]
  const float* bias[7];
  u16 *q_buf, *k_buf, *va_t, *x_buf, *g_buf;
  float* out;
};

__global__ __launch_bounds__(256, 4) void gemm_dma(ArgsD P, int unit_override) {
  __shared__ __align__(16) u16 As[2][128 * 64];
  __shared__ __align__(16) u16 Bs[2][128 * 64];

  int unit, bid;
  if (unit_override >= 0) { unit = unit_override; bid = blockIdx.x; }
  else { unit = blockIdx.x >> 8; bid = blockIdx.x & 255; }
  const int bm = bid & 31;
  const int bn = bid >> 5;

  const int tid = threadIdx.x;
  const int lane = tid & 63;
  const int wid = tid >> 6;
  const int wq = wid >> 1, wn = wid & 1;
  const int cl = lane & 15;
  const int gl = lane >> 4;

  const u16 *A0, *A1 = nullptr, *Wp;
  const float* bp;
  int nkt, mode;  // nkt in BK=64 steps
  switch (unit) {
    case 0: A0 = P.act[0]; A1 = P.act[1]; Wp = P.W[5]; bp = P.bias[5]; nkt = 32; mode = 0; break;
    case 1: A0 = P.act[0]; Wp = P.W[0]; bp = P.bias[0]; nkt = 16; mode = 1; break;
    case 2: A0 = P.act[1]; Wp = P.W[1]; bp = P.bias[1]; nkt = 16; mode = 2; break;
    case 3: A0 = P.act[2]; Wp = P.W[2]; bp = P.bias[2]; nkt = 16; mode = 3; break;
    case 4: A0 = P.act[3]; Wp = P.W[3]; bp = P.bias[3]; nkt = 16; mode = 4; break;
    case 5: A0 = P.act[4]; Wp = P.W[4]; bp = P.bias[4]; nkt = 16; mode = 5; break;
    default: A0 = P.x_buf; Wp = P.W[6]; bp = P.bias[6]; nkt = 16; mode = 6; break;
  }
  const int K = nkt * 64;  // B-row stride; A-row stride is always 1024

  f32x4 acc[4][4];
  const f32x4 vzero = {0.f, 0.f, 0.f, 0.f};
#pragma unroll
  for (int i = 0; i < 4; i++)
#pragma unroll
    for (int j = 0; j < 4; j++) acc[i][j] = vzero;

  // DMA geometry: instr i of wave w writes LDS u16 [(w*4+i)*512, +512);
  // lane l -> row (w*4+i)*8 + (l>>3); global col swizzled.
  int drow[4];
#pragma unroll
  for (int i = 0; i < 4; ++i) drow[i] = (wid * 4 + i) * 8 + (lane >> 3);
  const int dcolsw = (((lane & 7) ^ (lane >> 3)) << 3);  // u16 units

  auto STAGE = [&](int kt, int buf) {
    const u16* Ab;
    int akoff;
    if (A1 && kt >= 16) { Ab = A1; akoff = (kt - 16) * 64; }
    else { Ab = A0; akoff = kt * 64; }
#pragma unroll
    for (int i = 0; i < 4; ++i) {
      gload_lds16(Ab + (size_t)(bm * 128 + drow[i]) * 1024 + akoff + dcolsw,
                  &As[buf][(wid * 4 + i) * 512]);
      gload_lds16(Wp + (size_t)(bn * 128 + drow[i]) * K + kt * 64 + dcolsw,
                  &Bs[buf][(wid * 4 + i) * 512]);
    }
  };

  STAGE(0, 0);

  for (int kt = 0; kt < nkt; ++kt) {
    const int cur = kt & 1;
    __builtin_amdgcn_sched_barrier(0);
    __builtin_amdgcn_s_barrier();  // all prev-iter LDS reads complete
    if (kt + 1 < nkt) {
      STAGE(kt + 1, cur ^ 1);
      asm volatile("s_waitcnt vmcnt(8)" ::: "memory");  // own tile-kt loads done
    } else {
      asm volatile("s_waitcnt vmcnt(0)" ::: "memory");
    }
    __builtin_amdgcn_s_barrier();  // all waves' tile-kt data arrived
    __builtin_amdgcn_sched_barrier(0);

#pragma unroll
    for (int kk = 0; kk < 2; ++kk) {
      bf16x8 af[4], bfr[4];
      const int slot = ((kk * 4 + gl) ^ (cl & 7)) << 3;  // swizzled col, u16
#pragma unroll
      for (int mi = 0; mi < 4; mi++)
        af[mi] = *(const bf16x8*)(const void*)&As[cur][(wq * 64 + mi * 16 + cl) * 64 + slot];
#pragma unroll
      for (int nj = 0; nj < 4; nj++)
        bfr[nj] = *(const bf16x8*)(const void*)&Bs[cur][(wn * 64 + nj * 16 + cl) * 64 + slot];
#pragma unroll
      for (int mi = 0; mi < 4; mi++)
#pragma unroll
        for (int nj = 0; nj < 4; nj++)
          acc[mi][nj] = __builtin_amdgcn_mfma_f32_16x16x32_bf16(af[mi], bfr[nj], acc[mi][nj], 0, 0, 0);
    }
  }

  // epilogue (C/D: col = lane&15, row = (lane>>4)*4 + reg)
  const int rowbase = bm * 128 + wq * 64;
  const int colbase = bn * 128 + wn * 64;
#pragma unroll
  for (int mi = 0; mi < 4; mi++) {
#pragma unroll
    for (int nj = 0; nj < 4; nj++) {
      const int gn = colbase + nj * 16 + cl;
      const float bias = bp[gn];
      const int gm0 = rowbase + mi * 16 + gl * 4;
      if (mode == 0) {
#pragma unroll
        for (int r = 0; r < 4; r++) {
          float v = acc[mi][nj][r] + bias;
          float s = 1.0f / (1.0f + __expf(-v));
          size_t idx = (size_t)(gm0 + r) * 1024 + gn;
          if (P.g_buf) P.g_buf[idx] = f2bf(s);
          else P.out[idx] = s;
        }
      } else if (mode <= 4) {
        u16* dst = (mode <= 2) ? P.q_buf : P.k_buf;
        const int part = (mode == 2 || mode == 4) ? 1 : 0;
        const int h = gn >> 6, dk = gn & 63;
#pragma unroll
        for (int r = 0; r < 4; r++) {
          int gm = gm0 + r;
          int b = gm >> 10, s = gm & 1023;
          dst[(((size_t)(b * 16 + h)) * 1024 + s) * 128 + part * 64 + dk] =
              f2bf(acc[mi][nj][r] + bias);
        }
      } else if (mode == 5) {
        const int h = gn >> 6, dk = gn & 63;
        int b = gm0 >> 10, s = gm0 & 1023;
        ushort4 pk;
        pk.x = f2bf(acc[mi][nj][0] + bias);
        pk.y = f2bf(acc[mi][nj][1] + bias);
        pk.z = f2bf(acc[mi][nj][2] + bias);
        pk.w = f2bf(acc[mi][nj][3] + bias);
        *(ushort4*)&P.va_t[(((size_t)(b * 16 + h)) * 64 + dk) * 1024 + s] = pk;
      } else {
#pragma unroll
        for (int r = 0; r < 4; r++) {
          size_t idx = (size_t)(gm0 + r) * 1024 + gn;
          float g = P.g_buf ? bf2f(P.g_buf[idx]) : P.out[idx];
          P.out[idx] = (acc[mi][nj][r] + bias) * g;
        }
      }
    }
  }
}

// ---------------------------------------------------------------------------
// LEGACY reg-staged GEMM (fallback when ws too small) — verified R6/R11.
// ---------------------------------------------------------------------------
struct Args {
  const float* act[5];
  const float* W[7];
  const float* bias[7];
  u16 *q_buf, *k_buf, *va_t, *x_buf, *g_buf;
  float* out;
};

__global__ __launch_bounds__(256, 2) void gemm_kernel(Args P, int unit_override) {
  __shared__ __align__(16) u16 As[128 * 40];
  __shared__ __align__(16) u16 Bs[128 * 40];

  int unit, bid;
  if (unit_override >= 0) { unit = unit_override; bid = blockIdx.x; }
  else { unit = blockIdx.x >> 8; bid = blockIdx.x & 255; }
  const int bm = bid & 31;
  const int bn = bid >> 5;

  const int tid = threadIdx.x;
  const int lane = tid & 63;
  const int wid = tid >> 6;
  const int wq = wid >> 1, wn = wid & 1;
  const int cl = lane & 15;
  const int gl = lane >> 4;

  const float *A0, *A1 = nullptr, *Wp, *bp;
  int nkt, mode;
  switch (unit) {
    case 0: A0 = P.act[0]; A1 = P.act[1]; Wp = P.W[5]; bp = P.bias[5]; nkt = 64; mode = 0; break;
    case 1: A0 = P.act[0]; Wp = P.W[0]; bp = P.bias[0]; nkt = 32; mode = 1; break;
    case 2: A0 = P.act[1]; Wp = P.W[1]; bp = P.bias[1]; nkt = 32; mode = 2; break;
    case 3: A0 = P.act[2]; Wp = P.W[2]; bp = P.bias[2]; nkt = 32; mode = 3; break;
    case 4: A0 = P.act[3]; Wp = P.W[3]; bp = P.bias[3]; nkt = 32; mode = 4; break;
    case 5: A0 = P.act[4]; Wp = P.W[4]; bp = P.bias[4]; nkt = 32; mode = 5; break;
    default: A0 = nullptr; Wp = P.W[6]; bp = P.bias[6]; nkt = 32; mode = 6; break;
  }
  const int K = nkt * 32;

  f32x4 acc[4][4];
  const f32x4 vzero = {0.f, 0.f, 0.f, 0.f};
#pragma unroll
  for (int i = 0; i < 4; i++)
#pragma unroll
    for (int j = 0; j < 4; j++) acc[i][j] = vzero;

  int arow[2], apn[2];
#pragma unroll
  for (int j = 0; j < 2; j++) {
    int f = (wid * 2 + j) * 64 + lane;
    arow[j] = f >> 2;
    apn[j] = f & 3;
  }

  float4 ra[2][2], rb[2][2];
  bf16x8 ra6[2];

  auto stage = [&](int kt) {
    const float* Abase;
    int akoff;
    if (A1 && kt >= 32) { Abase = A1; akoff = (kt - 32) * 32; }
    else { Abase = A0; akoff = kt * 32; }
#pragma unroll
    for (int j = 0; j < 2; j++) {
      size_t ae = (size_t)(bm * 128 + arow[j]) * 1024 + akoff + apn[j] * 8;
      size_t we = (size_t)(bn * 128 + arow[j]) * K + kt * 32 + apn[j] * 8;
      if (mode == 6) {
        ra6[j] = *(const bf16x8*)(const void*)(P.x_buf + ae);
      } else {
        const float* p = Abase + ae;
        ra[j][0] = *(const float4*)(const void*)p;
        ra[j][1] = *(const float4*)(const void*)(p + 4);
      }
      const float* q = Wp + we;
      rb[j][0] = *(const float4*)(const void*)q;
      rb[j][1] = *(const float4*)(const void*)(q + 4);
    }
  };

  stage(0);

  for (int kt = 0; kt < nkt; kt++) {
    __syncthreads();
#pragma unroll
    for (int j = 0; j < 2; j++) {
      *(bf16x8*)(void*)&As[arow[j] * 40 + apn[j] * 8] =
          (mode == 6) ? ra6[j] : cvt8(ra[j][0], ra[j][1]);
      *(bf16x8*)(void*)&Bs[arow[j] * 40 + apn[j] * 8] = cvt8(rb[j][0], rb[j][1]);
    }
    __syncthreads();

    bf16x8 af[4], bfr[4];
#pragma unroll
    for (int mi = 0; mi < 4; mi++)
      af[mi] = *(const bf16x8*)(const void*)&As[(wq * 64 + mi * 16 + cl) * 40 + gl * 8];
#pragma unroll
    for (int nj = 0; nj < 4; nj++)
      bfr[nj] = *(const bf16x8*)(const void*)&Bs[(wn * 64 + nj * 16 + cl) * 40 + gl * 8];

    if (kt + 1 < nkt) stage(kt + 1);

#pragma unroll
    for (int mi = 0; mi < 4; mi++)
#pragma unroll
      for (int nj = 0; nj < 4; nj++)
        acc[mi][nj] = __builtin_amdgcn_mfma_f32_16x16x32_bf16(af[mi], bfr[nj], acc[mi][nj], 0, 0, 0);
  }

  const int rowbase = bm * 128 + wq * 64;
  const int colbase = bn * 128 + wn * 64;
#pragma unroll
  for (int mi = 0; mi < 4; mi++) {
#pragma unroll
    for (int nj = 0; nj < 4; nj++) {
      const int gn = colbase + nj * 16 + cl;
      const float bias = bp[gn];
      const int gm0 = rowbase + mi * 16 + gl * 4;
      if (mode == 0) {
#pragma unroll
        for (int r = 0; r < 4; r++) {
          float v = acc[mi][nj][r] + bias;
          float s = 1.0f / (1.0f + __expf(-v));
          size_t idx = (size_t)(gm0 + r) * 1024 + gn;
          if (P.g_buf) P.g_buf[idx] = f2bf(s);
          else P.out[idx] = s;
        }
      } else if (mode <= 4) {
        u16* dst = (mode <= 2) ? P.q_buf : P.k_buf;
        const int part = (mode == 2 || mode == 4) ? 1 : 0;
        const int h = gn >> 6, dk = gn & 63;
#pragma unroll
        for (int r = 0; r < 4; r++) {
          int gm = gm0 + r;
          int b = gm >> 10, s = gm & 1023;
          dst[(((size_t)(b * 16 + h)) * 1024 + s) * 128 + part * 64 + dk] =
              f2bf(acc[mi][nj][r] + bias);
        }
      } else if (mode == 5) {
        const int h = gn >> 6, dk = gn & 63;
        int b = gm0 >> 10, s = gm0 & 1023;
        ushort4 pk;
        pk.x = f2bf(acc[mi][nj][0] + bias);
        pk.y = f2bf(acc[mi][nj][1] + bias);
        pk.z = f2bf(acc[mi][nj][2] + bias);
        pk.w = f2bf(acc[mi][nj][3] + bias);
        *(ushort4*)&P.va_t[(((size_t)(b * 16 + h)) * 64 + dk) * 1024 + s] = pk;
      } else {
#pragma unroll
        for (int r = 0; r < 4; r++) {
          size_t idx = (size_t)(gm0 + r) * 1024 + gn;
          float g = P.g_buf ? bf2f(P.g_buf[idx]) : P.out[idx];
          P.out[idx] = (acc[mi][nj][r] + bias) * g;
        }
      }
    }
  }
}

// ---------------------------------------------------------------------------
// Attention: flags != nullptr -> load precomputed per-ktile flags (no scan).
// Verified R10 (354us pass).
// ---------------------------------------------------------------------------
__global__ __launch_bounds__(256, 2) void attn_kernel(const u16* __restrict__ q_buf,
                                                      const u16* __restrict__ k_buf,
                                                      const u16* __restrict__ va_t,
                                                      const int* __restrict__ mask,
                                                      const int* __restrict__ flags,
                                                      u16* __restrict__ x_buf) {
  __shared__ __align__(16) u16 Ks[64 * 136];
  __shared__ __align__(16) u16 Vs[64 * 72];
  __shared__ __align__(16) u16 Ps[4 * 32 * 72];
  __shared__ int mflags[16];

  const int tid = threadIdx.x;
  const int lane = tid & 63;
  const int wid = tid >> 6;
  const int cl = lane & 15;
  const int gl = lane >> 4;

  const int qt = blockIdx.x & 7;
  const int bh = blockIdx.x >> 3;
  const int b = bh >> 4, h = bh & 15;
  const u16* qh = q_buf + (size_t)bh * 1024 * 128;
  const u16* kh = k_buf + (size_t)bh * 1024 * 128;
  const u16* vh = va_t + (size_t)bh * 64 * 1024;
  const int s0 = qt * 128;

  if (flags) {
    if (tid < 16) mflags[tid] = flags[(b * 8 + qt) * 16 + tid];
    __syncthreads();
  } else {
    if (tid < 16) mflags[tid] = 1;
    __syncthreads();
    const int* mbase = mask + ((size_t)b * 1024 + s0) * 1024 + tid * 4;
    int ok = 1;
#pragma unroll 4
    for (int i = 0; i < 128; i++) {
      const int4 m4 = *(const int4*)(const void*)(mbase + (size_t)i * 1024);
      if (!(m4.x && m4.y && m4.z && m4.w)) ok = 0;
    }
    if (!ok) atomicAnd(&mflags[tid >> 4], 0);
    __syncthreads();
  }

  bf16x8 aq[2][4];
#pragma unroll
  for (int mi = 0; mi < 2; mi++) {
    int row = s0 + wid * 32 + mi * 16 + cl;
#pragma unroll
    for (int kk = 0; kk < 4; kk++)
      aq[mi][kk] = *(const bf16x8*)(const void*)&qh[(size_t)row * 128 + kk * 32 + gl * 8];
  }

  f32x4 acc_o[2][4];
  float l_part[2][4];
  const f32x4 vzero = {0.f, 0.f, 0.f, 0.f};
#pragma unroll
  for (int mi = 0; mi < 2; mi++) {
#pragma unroll
    for (int nj = 0; nj < 4; nj++) acc_o[mi][nj] = vzero;
#pragma unroll
    for (int r = 0; r < 4; r++) l_part[mi][r] = 0.f;
  }

  const float scale = 0.08838834764831845f;
  u16* pw = &Ps[wid * 32 * 72];

  int krow[4], kp[4], vrow[2], vp[2];
#pragma unroll
  for (int j = 0; j < 4; j++) {
    int f = (wid * 4 + j) * 64 + lane;
    krow[j] = f >> 4; kp[j] = f & 15;
  }
#pragma unroll
  for (int j = 0; j < 2; j++) {
    int f = (wid * 2 + j) * 64 + lane;
    vrow[j] = f >> 3; vp[j] = f & 7;
  }

  bf16x8 kv[4], vv[2];
  auto stageKV = [&](int kt) {
#pragma unroll
    for (int j = 0; j < 4; j++)
      kv[j] = *(const bf16x8*)(const void*)&kh[(size_t)(kt * 64 + krow[j]) * 128 + kp[j] * 8];
#pragma unroll
    for (int j = 0; j < 2; j++)
      vv[j] = *(const bf16x8*)(const void*)&vh[(size_t)vrow[j] * 1024 + kt * 64 + vp[j] * 8];
  };

  stageKV(0);

  for (int kt = 0; kt < 16; kt++) {
    __syncthreads();
#pragma unroll
    for (int j = 0; j < 4; j++)
      *(bf16x8*)(void*)&Ks[krow[j] * 136 + kp[j] * 8] = kv[j];
#pragma unroll
    for (int j = 0; j < 2; j++)
      *(bf16x8*)(void*)&Vs[vrow[j] * 72 + vp[j] * 8] = vv[j];
    __syncthreads();

    if (kt < 15) stageKV(kt + 1);

    f32x4 sc[2][4];
#pragma unroll
    for (int mi = 0; mi < 2; mi++)
#pragma unroll
      for (int nj = 0; nj < 4; nj++) sc[mi][nj] = vzero;
#pragma unroll
    for (int kk = 0; kk < 4; kk++) {
      bf16x8 bk[4];
#pragma unroll
      for (int nj = 0; nj < 4; nj++)
        bk[nj] = *(const bf16x8*)(const void*)&Ks[(nj * 16 + cl) * 136 + (kk * 4 + gl) * 8];
#pragma unroll
      for (int mi = 0; mi < 2; mi++)
#pragma unroll
        for (int nj = 0; nj < 4; nj++)
          sc[mi][nj] = __builtin_amdgcn_mfma_f32_16x16x32_bf16(aq[mi][kk], bk[nj], sc[mi][nj], 0, 0, 0);
    }

    const bool fastm = (mflags[kt] != 0);
#pragma unroll
    for (int mi = 0; mi < 2; mi++) {
#pragma unroll
      for (int nj = 0; nj < 4; nj++) {
        int key = kt * 64 + nj * 16 + cl;
#pragma unroll
        for (int r = 0; r < 4; r++) {
          int lrow = mi * 16 + gl * 4 + r;
          float sv = fminf(sc[mi][nj][r] * scale, 30.0f);
          float pv;
          if (fastm) {
            pv = __expf(sv);
          } else {
            int qrow = s0 + wid * 32 + lrow;
            int mv = mask[((size_t)b * 1024 + qrow) * 1024 + key];
            pv = (mv != 0) ? __expf(sv) : 0.0f;
          }
          l_part[mi][r] += pv;
          pw[lrow * 72 + nj * 16 + cl] = f2bf(pv);
        }
      }
    }

#pragma unroll
    for (int kk = 0; kk < 2; kk++) {
      bf16x8 ap[2], bv[4];
#pragma unroll
      for (int mi = 0; mi < 2; mi++)
        ap[mi] = *(const bf16x8*)(const void*)&pw[(mi * 16 + cl) * 72 + kk * 32 + gl * 8];
#pragma unroll
      for (int nj = 0; nj < 4; nj++)
        bv[nj] = *(const bf16x8*)(const void*)&Vs[(nj * 16 + cl) * 72 + (kk * 4 + gl) * 8];
#pragma unroll
      for (int mi = 0; mi < 2; mi++)
#pragma unroll
        for (int nj = 0; nj < 4; nj++)
          acc_o[mi][nj] = __builtin_amdgcn_mfma_f32_16x16x32_bf16(ap[mi], bv[nj], acc_o[mi][nj], 0, 0, 0);
    }
  }

#pragma unroll
  for (int mi = 0; mi < 2; mi++)
#pragma unroll
    for (int r = 0; r < 4; r++) {
      float s = l_part[mi][r];
      s += __shfl_xor(s, 1);
      s += __shfl_xor(s, 2);
      s += __shfl_xor(s, 4);
      s += __shfl_xor(s, 8);
      l_part[mi][r] = 1.0f / s;
    }

#pragma unroll
  for (int mi = 0; mi < 2; mi++)
#pragma unroll
    for (int nj = 0; nj < 4; nj++)
#pragma unroll
      for (int r = 0; r < 4; r++) {
        int srow = s0 + wid * 32 + mi * 16 + gl * 4 + r;
        int dv = nj * 16 + cl;
        float v = acc_o[mi][nj][r] * l_part[mi][r];
        x_buf[((size_t)b * 1024 + srow) * 1024 + h * 64 + dv] = f2bf(v);
      }
}

// ---------------------------------------------------------------------------
extern "C" void kernel_launch(void* const* d_in, const int* in_sizes, int n_in,
                              void* d_out, int out_size, void* d_ws, size_t ws_size,
                              hipStream_t stream) {
  (void)in_sizes; (void)n_in; (void)out_size;
  const int* mask = (const int*)d_in[5];

  char* ws = (char*)d_ws;
  u16* q_buf = (u16*)(ws);
  u16* k_buf = (u16*)(ws + ((size_t)16 << 20));
  u16* va_t  = (u16*)(ws + ((size_t)32 << 20));
  u16* x_buf = (u16*)(ws + ((size_t)40 << 20));
  u16* g_buf = (ws_size >= ((size_t)56 << 20)) ? (u16*)(ws + ((size_t)48 << 20)) : nullptr;

  // input index maps (act order: qa, qg, ka, kg, va; W order: Wqa,Wqg,Wka,Wkg,Wva,Wgate,Winfo)
  const int act_idx[5] = {2, 0, 3, 1, 4};
  const int w_idx[7] = {10, 6, 12, 8, 14, 16, 18};
  const int b_idx[7] = {11, 7, 13, 9, 15, 17, 19};

  const bool big = (ws_size >= ((size_t)112 << 20)) && (g_buf != nullptr);
  int* flags = (ws_size >= ((size_t)112 << 20) + 4096) ? (int*)(ws + ((size_t)112 << 20)) : nullptr;

  if (big) {
    // bf16 buffers: acts @56MB (5 x 8MB), W0-4 @96MB (2MB ea), Wgate @106MB (4MB), Winfo @110MB (2MB)
    u16* actb[5];
    for (int i = 0; i < 5; i++) actb[i] = (u16*)(ws + ((size_t)56 << 20) + (size_t)i * (8 << 20));
    u16* wb[7];
    for (int i = 0; i < 5; i++) wb[i] = (u16*)(ws + ((size_t)96 << 20) + (size_t)i * (2 << 20));
    wb[5] = (u16*)(ws + ((size_t)106 << 20));
    wb[6] = (u16*)(ws + ((size_t)110 << 20));

    CvtArgs C;
    for (int i = 0; i < 5; i++) {
      C.src[i] = (const float*)d_in[act_idx[i]];
      C.dst[i] = actb[i];
      C.n8[i] = (4096 * 1024) / 8;
    }
    for (int i = 0; i < 7; i++) {
      C.src[5 + i] = (const float*)d_in[w_idx[i]];
      C.dst[5 + i] = wb[i];
      C.n8[5 + i] = ((i == 5) ? (1024 * 2048) : (1024 * 1024)) / 8;
    }
    if (flags) hipLaunchKernelGGL(maskflags_kernel, dim3(512), dim3(256), 0, stream, mask, flags);
    hipLaunchKernelGGL(cvt_kernel, dim3(2048), dim3(256), 0, stream, C);

    ArgsD P;
    for (int i = 0; i < 5; i++) P.act[i] = actb[i];
    for (int i = 0; i < 7; i++) { P.W[i] = wb[i]; P.bias[i] = (const float*)d_in[b_idx[i]]; }
    P.q_buf = q_buf; P.k_buf = k_buf; P.va_t = va_t; P.x_buf = x_buf;
    P.g_buf = g_buf; P.out = (float*)d_out;

    hipLaunchKernelGGL(gemm_dma, dim3(1536), dim3(256), 0, stream, P, -1);
    hipLaunchKernelGGL(attn_kernel, dim3(512), dim3(256), 0, stream,
                       q_buf, k_buf, va_t, mask, flags, x_buf);
    hipLaunchKernelGGL(gemm_dma, dim3(256), dim3(256), 0, stream, P, 6);
  } else {
    Args P;
    for (int i = 0; i < 5; i++) P.act[i] = (const float*)d_in[act_idx[i]];
    for (int i = 0; i < 7; i++) { P.W[i] = (const float*)d_in[w_idx[i]]; P.bias[i] = (const float*)d_in[b_idx[i]]; }
    P.q_buf = q_buf; P.k_buf = k_buf; P.va_t = va_t; P.x_buf = x_buf;
    P.g_buf = g_buf; P.out = (float*)d_out;

    hipLaunchKernelGGL(gemm_kernel, dim3(1536), dim3(256), 0, stream, P, -1);
    hipLaunchKernelGGL(attn_kernel, dim3(512), dim3(256), 0, stream,
                       q_buf, k_buf, va_t, mask, (const int*)nullptr, x_buf);
    hipLaunchKernelGGL(gemm_kernel, dim3(256), dim3(256), 0, stream, P, 6);
  }
}

// Round 21
// 352.928 us; speedup vs baseline: 1.0213x; 1.0213x over previous
//
#include <hip/hip_runtime.h>

// BoxMultiHeadedAttention: B=4, S=1024, D=1024, H=16, DK=64.
// FINAL (R27): best-known recombination. gemm_dma = R8-exact (BK=32, 2-buffer,
// 32KB LDS, counted vmcnt(4)) measured 89.4us; attn = R10 maskflags path
// (354.4us total best). L1 proven occupancy-bound (R8/R10/R13 curve); swizzle
// and deeper pipelines proven non-critical at this occupancy.

typedef unsigned short u16;
typedef __bf16 bf16x8 __attribute__((ext_vector_type(8)));
typedef float f32x4 __attribute__((ext_vector_type(4)));

#define DEV static __device__ __forceinline__

DEV u16 f2bf(float x) {
  union { __bf16 h; u16 u; } c;
  c.h = (__bf16)x;
  return c.u;
}
DEV float bf2f(u16 h) { return __uint_as_float(((unsigned)h) << 16); }

DEV bf16x8 cvt8(float4 a, float4 b) {
  bf16x8 v;
  v[0] = (__bf16)a.x; v[1] = (__bf16)a.y; v[2] = (__bf16)a.z; v[3] = (__bf16)a.w;
  v[4] = (__bf16)b.x; v[5] = (__bf16)b.y; v[6] = (__bf16)b.z; v[7] = (__bf16)b.w;
  return v;
}

DEV void gload_lds16(const void* g, void* l) {
  __builtin_amdgcn_global_load_lds(
      (const __attribute__((address_space(1))) void*)g,
      (__attribute__((address_space(3))) void*)l, 16, 0, 0);
}

// ---------------------------------------------------------------------------
// fp32 -> bf16 pre-conversion (12 segments: 5 acts, 7 weights)
// ---------------------------------------------------------------------------
struct CvtArgs {
  const float* src[12];
  u16* dst[12];
  int n8[12];  // elem count / 8
};

__global__ __launch_bounds__(256) void cvt_kernel(CvtArgs C) {
  const int stride = gridDim.x * blockDim.x;
#pragma unroll 1
  for (int s = 0; s < 12; ++s) {
    const float4* src = (const float4*)C.src[s];
    u16* dst = C.dst[s];
    const int n8 = C.n8[s];
    for (int i = blockIdx.x * blockDim.x + threadIdx.x; i < n8; i += stride) {
      const float4 a = src[i * 2];
      const float4 b = src[i * 2 + 1];
      *(bf16x8*)(void*)(dst + (size_t)i * 8) = cvt8(a, b);
    }
  }
}

// ---------------------------------------------------------------------------
// mask all-nonzero flags per (b, qtile128, ktile64): 4 x 8 x 16 = 512 flags.
// Verified R10 (354us pass).
// ---------------------------------------------------------------------------
__global__ __launch_bounds__(256) void maskflags_kernel(const int* __restrict__ mask,
                                                        int* __restrict__ flags) {
  const int bid = blockIdx.x;  // b*128 + qt*16 + kt
  const int kt = bid & 15, qt = (bid >> 4) & 7, b = bid >> 7;
  const int tid = threadIdx.x;
  __shared__ int f;
  if (tid == 0) f = 1;
  __syncthreads();
  int ok = 1;
  const int c = tid & 15;
  const int r0 = tid >> 4;
#pragma unroll
  for (int p = 0; p < 8; ++p) {
    const int row = qt * 128 + p * 16 + r0;
    const int4 m4 = *(const int4*)(const void*)(
        mask + ((size_t)b * 1024 + row) * 1024 + kt * 64 + c * 4);
    if (!(m4.x && m4.y && m4.z && m4.w)) ok = 0;
  }
  if (!ok) atomicAnd(&f, 0);
  __syncthreads();
  if (tid == 0) flags[bid] = f;
}

// ---------------------------------------------------------------------------
// DMA-path GEMM (R8-exact, measured 89.4us): A,W pre-converted bf16.
// 128x128 tile, BK=32, 4 waves 2x2. LDS: linear [128][32] bf16 tiles,
// double-buffered (32 KB). global_load_lds width=16 (4 instr/wave/K-step);
// counted vmcnt(4) keeps next tile in flight across the barrier.
// ---------------------------------------------------------------------------
struct ArgsD {
  const u16* act[5];   // bf16 [4096][1024]
  const u16* W[7];     // bf16 [N][K]
  const float* bias[7];
  u16 *q_buf, *k_buf, *va_t, *x_buf, *g_buf;
  float* out;
};

__global__ __launch_bounds__(256, 4) void gemm_dma(ArgsD P, int unit_override) {
  __shared__ __align__(16) u16 As[2][128 * 32];
  __shared__ __align__(16) u16 Bs[2][128 * 32];

  int unit, bid;
  if (unit_override >= 0) { unit = unit_override; bid = blockIdx.x; }
  else { unit = blockIdx.x >> 8; bid = blockIdx.x & 255; }
  const int bm = bid & 31;
  const int bn = bid >> 5;

  const int tid = threadIdx.x;
  const int lane = tid & 63;
  const int wid = tid >> 6;
  const int wq = wid >> 1, wn = wid & 1;
  const int cl = lane & 15;
  const int gl = lane >> 4;

  const u16 *A0, *A1 = nullptr, *Wp;
  const float* bp;
  int nkt, mode;
  switch (unit) {
    case 0: A0 = P.act[0]; A1 = P.act[1]; Wp = P.W[5]; bp = P.bias[5]; nkt = 64; mode = 0; break;
    case 1: A0 = P.act[0]; Wp = P.W[0]; bp = P.bias[0]; nkt = 32; mode = 1; break;
    case 2: A0 = P.act[1]; Wp = P.W[1]; bp = P.bias[1]; nkt = 32; mode = 2; break;
    case 3: A0 = P.act[2]; Wp = P.W[2]; bp = P.bias[2]; nkt = 32; mode = 3; break;
    case 4: A0 = P.act[3]; Wp = P.W[3]; bp = P.bias[3]; nkt = 32; mode = 4; break;
    case 5: A0 = P.act[4]; Wp = P.W[4]; bp = P.bias[4]; nkt = 32; mode = 5; break;
    default: A0 = P.x_buf; Wp = P.W[6]; bp = P.bias[6]; nkt = 32; mode = 6; break;
  }
  const int K = nkt * 32;  // B-row stride; A-row stride is always 1024

  f32x4 acc[4][4];
  const f32x4 vzero = {0.f, 0.f, 0.f, 0.f};
#pragma unroll
  for (int i = 0; i < 4; i++)
#pragma unroll
    for (int j = 0; j < 4; j++) acc[i][j] = vzero;

  // DMA geometry: instr i of wave w writes LDS u16 [(w*2+i)*512, +512);
  // lane l covers row (w*2+i)*16 + l/4, cols [(l&3)*8, +8).
  int drow[2];
  const int dcol = (lane & 3) * 8;
  drow[0] = (wid * 2 + 0) * 16 + (lane >> 2);
  drow[1] = (wid * 2 + 1) * 16 + (lane >> 2);

  auto STAGE = [&](int kt, int buf) {
    const u16* Ab;
    int akoff;
    if (A1 && kt >= 32) { Ab = A1; akoff = (kt - 32) * 32; }
    else { Ab = A0; akoff = kt * 32; }
#pragma unroll
    for (int i = 0; i < 2; ++i) {
      gload_lds16(Ab + (size_t)(bm * 128 + drow[i]) * 1024 + akoff + dcol,
                  &As[buf][(wid * 2 + i) * 512]);
      gload_lds16(Wp + (size_t)(bn * 128 + drow[i]) * K + kt * 32 + dcol,
                  &Bs[buf][(wid * 2 + i) * 512]);
    }
  };

  STAGE(0, 0);

  for (int kt = 0; kt < nkt; ++kt) {
    const int cur = kt & 1;
    __builtin_amdgcn_sched_barrier(0);
    __builtin_amdgcn_s_barrier();  // all prev-iter LDS reads complete
    if (kt + 1 < nkt) {
      STAGE(kt + 1, cur ^ 1);
      asm volatile("s_waitcnt vmcnt(4)" ::: "memory");  // own cur-tile loads done
    } else {
      asm volatile("s_waitcnt vmcnt(0)" ::: "memory");
    }
    __builtin_amdgcn_s_barrier();  // all waves' cur-tile data arrived
    __builtin_amdgcn_sched_barrier(0);

    bf16x8 af[4], bfr[4];
#pragma unroll
    for (int mi = 0; mi < 4; mi++)
      af[mi] = *(const bf16x8*)(const void*)&As[cur][(wq * 64 + mi * 16 + cl) * 32 + gl * 8];
#pragma unroll
    for (int nj = 0; nj < 4; nj++)
      bfr[nj] = *(const bf16x8*)(const void*)&Bs[cur][(wn * 64 + nj * 16 + cl) * 32 + gl * 8];

#pragma unroll
    for (int mi = 0; mi < 4; mi++)
#pragma unroll
      for (int nj = 0; nj < 4; nj++)
        acc[mi][nj] = __builtin_amdgcn_mfma_f32_16x16x32_bf16(af[mi], bfr[nj], acc[mi][nj], 0, 0, 0);
  }

  // epilogue (C/D: col = lane&15, row = (lane>>4)*4 + reg)
  const int rowbase = bm * 128 + wq * 64;
  const int colbase = bn * 128 + wn * 64;
#pragma unroll
  for (int mi = 0; mi < 4; mi++) {
#pragma unroll
    for (int nj = 0; nj < 4; nj++) {
      const int gn = colbase + nj * 16 + cl;
      const float bias = bp[gn];
      const int gm0 = rowbase + mi * 16 + gl * 4;
      if (mode == 0) {
#pragma unroll
        for (int r = 0; r < 4; r++) {
          float v = acc[mi][nj][r] + bias;
          float s = 1.0f / (1.0f + __expf(-v));
          size_t idx = (size_t)(gm0 + r) * 1024 + gn;
          if (P.g_buf) P.g_buf[idx] = f2bf(s);
          else P.out[idx] = s;
        }
      } else if (mode <= 4) {
        u16* dst = (mode <= 2) ? P.q_buf : P.k_buf;
        const int part = (mode == 2 || mode == 4) ? 1 : 0;
        const int h = gn >> 6, dk = gn & 63;
#pragma unroll
        for (int r = 0; r < 4; r++) {
          int gm = gm0 + r;
          int b = gm >> 10, s = gm & 1023;
          dst[(((size_t)(b * 16 + h)) * 1024 + s) * 128 + part * 64 + dk] =
              f2bf(acc[mi][nj][r] + bias);
        }
      } else if (mode == 5) {
        const int h = gn >> 6, dk = gn & 63;
        int b = gm0 >> 10, s = gm0 & 1023;
        ushort4 pk;
        pk.x = f2bf(acc[mi][nj][0] + bias);
        pk.y = f2bf(acc[mi][nj][1] + bias);
        pk.z = f2bf(acc[mi][nj][2] + bias);
        pk.w = f2bf(acc[mi][nj][3] + bias);
        *(ushort4*)&P.va_t[(((size_t)(b * 16 + h)) * 64 + dk) * 1024 + s] = pk;
      } else {
#pragma unroll
        for (int r = 0; r < 4; r++) {
          size_t idx = (size_t)(gm0 + r) * 1024 + gn;
          float g = P.g_buf ? bf2f(P.g_buf[idx]) : P.out[idx];
          P.out[idx] = (acc[mi][nj][r] + bias) * g;
        }
      }
    }
  }
}

// ---------------------------------------------------------------------------
// LEGACY reg-staged GEMM (fallback when ws too small) — verified R6/R11.
// ---------------------------------------------------------------------------
struct Args {
  const float* act[5];
  const float* W[7];
  const float* bias[7];
  u16 *q_buf, *k_buf, *va_t, *x_buf, *g_buf;
  float* out;
};

__global__ __launch_bounds__(256, 2) void gemm_kernel(Args P, int unit_override) {
  __shared__ __align__(16) u16 As[128 * 40];
  __shared__ __align__(16) u16 Bs[128 * 40];

  int unit, bid;
  if (unit_override >= 0) { unit = unit_override; bid = blockIdx.x; }
  else { unit = blockIdx.x >> 8; bid = blockIdx.x & 255; }
  const int bm = bid & 31;
  const int bn = bid >> 5;

  const int tid = threadIdx.x;
  const int lane = tid & 63;
  const int wid = tid >> 6;
  const int wq = wid >> 1, wn = wid & 1;
  const int cl = lane & 15;
  const int gl = lane >> 4;

  const float *A0, *A1 = nullptr, *Wp, *bp;
  int nkt, mode;
  switch (unit) {
    case 0: A0 = P.act[0]; A1 = P.act[1]; Wp = P.W[5]; bp = P.bias[5]; nkt = 64; mode = 0; break;
    case 1: A0 = P.act[0]; Wp = P.W[0]; bp = P.bias[0]; nkt = 32; mode = 1; break;
    case 2: A0 = P.act[1]; Wp = P.W[1]; bp = P.bias[1]; nkt = 32; mode = 2; break;
    case 3: A0 = P.act[2]; Wp = P.W[2]; bp = P.bias[2]; nkt = 32; mode = 3; break;
    case 4: A0 = P.act[3]; Wp = P.W[3]; bp = P.bias[3]; nkt = 32; mode = 4; break;
    case 5: A0 = P.act[4]; Wp = P.W[4]; bp = P.bias[4]; nkt = 32; mode = 5; break;
    default: A0 = nullptr; Wp = P.W[6]; bp = P.bias[6]; nkt = 32; mode = 6; break;
  }
  const int K = nkt * 32;

  f32x4 acc[4][4];
  const f32x4 vzero = {0.f, 0.f, 0.f, 0.f};
#pragma unroll
  for (int i = 0; i < 4; i++)
#pragma unroll
    for (int j = 0; j < 4; j++) acc[i][j] = vzero;

  int arow[2], apn[2];
#pragma unroll
  for (int j = 0; j < 2; j++) {
    int f = (wid * 2 + j) * 64 + lane;
    arow[j] = f >> 2;
    apn[j] = f & 3;
  }

  float4 ra[2][2], rb[2][2];
  bf16x8 ra6[2];

  auto stage = [&](int kt) {
    const float* Abase;
    int akoff;
    if (A1 && kt >= 32) { Abase = A1; akoff = (kt - 32) * 32; }
    else { Abase = A0; akoff = kt * 32; }
#pragma unroll
    for (int j = 0; j < 2; j++) {
      size_t ae = (size_t)(bm * 128 + arow[j]) * 1024 + akoff + apn[j] * 8;
      size_t we = (size_t)(bn * 128 + arow[j]) * K + kt * 32 + apn[j] * 8;
      if (mode == 6) {
        ra6[j] = *(const bf16x8*)(const void*)(P.x_buf + ae);
      } else {
        const float* p = Abase + ae;
        ra[j][0] = *(const float4*)(const void*)p;
        ra[j][1] = *(const float4*)(const void*)(p + 4);
      }
      const float* q = Wp + we;
      rb[j][0] = *(const float4*)(const void*)q;
      rb[j][1] = *(const float4*)(const void*)(q + 4);
    }
  };

  stage(0);

  for (int kt = 0; kt < nkt; kt++) {
    __syncthreads();
#pragma unroll
    for (int j = 0; j < 2; j++) {
      *(bf16x8*)(void*)&As[arow[j] * 40 + apn[j] * 8] =
          (mode == 6) ? ra6[j] : cvt8(ra[j][0], ra[j][1]);
      *(bf16x8*)(void*)&Bs[arow[j] * 40 + apn[j] * 8] = cvt8(rb[j][0], rb[j][1]);
    }
    __syncthreads();

    bf16x8 af[4], bfr[4];
#pragma unroll
    for (int mi = 0; mi < 4; mi++)
      af[mi] = *(const bf16x8*)(const void*)&As[(wq * 64 + mi * 16 + cl) * 40 + gl * 8];
#pragma unroll
    for (int nj = 0; nj < 4; nj++)
      bfr[nj] = *(const bf16x8*)(const void*)&Bs[(wn * 64 + nj * 16 + cl) * 40 + gl * 8];

    if (kt + 1 < nkt) stage(kt + 1);

#pragma unroll
    for (int mi = 0; mi < 4; mi++)
#pragma unroll
      for (int nj = 0; nj < 4; nj++)
        acc[mi][nj] = __builtin_amdgcn_mfma_f32_16x16x32_bf16(af[mi], bfr[nj], acc[mi][nj], 0, 0, 0);
  }

  const int rowbase = bm * 128 + wq * 64;
  const int colbase = bn * 128 + wn * 64;
#pragma unroll
  for (int mi = 0; mi < 4; mi++) {
#pragma unroll
    for (int nj = 0; nj < 4; nj++) {
      const int gn = colbase + nj * 16 + cl;
      const float bias = bp[gn];
      const int gm0 = rowbase + mi * 16 + gl * 4;
      if (mode == 0) {
#pragma unroll
        for (int r = 0; r < 4; r++) {
          float v = acc[mi][nj][r] + bias;
          float s = 1.0f / (1.0f + __expf(-v));
          size_t idx = (size_t)(gm0 + r) * 1024 + gn;
          if (P.g_buf) P.g_buf[idx] = f2bf(s);
          else P.out[idx] = s;
        }
      } else if (mode <= 4) {
        u16* dst = (mode <= 2) ? P.q_buf : P.k_buf;
        const int part = (mode == 2 || mode == 4) ? 1 : 0;
        const int h = gn >> 6, dk = gn & 63;
#pragma unroll
        for (int r = 0; r < 4; r++) {
          int gm = gm0 + r;
          int b = gm >> 10, s = gm & 1023;
          dst[(((size_t)(b * 16 + h)) * 1024 + s) * 128 + part * 64 + dk] =
              f2bf(acc[mi][nj][r] + bias);
        }
      } else if (mode == 5) {
        const int h = gn >> 6, dk = gn & 63;
        int b = gm0 >> 10, s = gm0 & 1023;
        ushort4 pk;
        pk.x = f2bf(acc[mi][nj][0] + bias);
        pk.y = f2bf(acc[mi][nj][1] + bias);
        pk.z = f2bf(acc[mi][nj][2] + bias);
        pk.w = f2bf(acc[mi][nj][3] + bias);
        *(ushort4*)&P.va_t[(((size_t)(b * 16 + h)) * 64 + dk) * 1024 + s] = pk;
      } else {
#pragma unroll
        for (int r = 0; r < 4; r++) {
          size_t idx = (size_t)(gm0 + r) * 1024 + gn;
          float g = P.g_buf ? bf2f(P.g_buf[idx]) : P.out[idx];
          P.out[idx] = (acc[mi][nj][r] + bias) * g;
        }
      }
    }
  }
}

// ---------------------------------------------------------------------------
// Attention: flags != nullptr -> load precomputed per-ktile flags (no scan).
// Verified R10 (354us pass).
// ---------------------------------------------------------------------------
__global__ __launch_bounds__(256, 2) void attn_kernel(const u16* __restrict__ q_buf,
                                                      const u16* __restrict__ k_buf,
                                                      const u16* __restrict__ va_t,
                                                      const int* __restrict__ mask,
                                                      const int* __restrict__ flags,
                                                      u16* __restrict__ x_buf) {
  __shared__ __align__(16) u16 Ks[64 * 136];
  __shared__ __align__(16) u16 Vs[64 * 72];
  __shared__ __align__(16) u16 Ps[4 * 32 * 72];
  __shared__ int mflags[16];

  const int tid = threadIdx.x;
  const int lane = tid & 63;
  const int wid = tid >> 6;
  const int cl = lane & 15;
  const int gl = lane >> 4;

  const int qt = blockIdx.x & 7;
  const int bh = blockIdx.x >> 3;
  const int b = bh >> 4, h = bh & 15;
  const u16* qh = q_buf + (size_t)bh * 1024 * 128;
  const u16* kh = k_buf + (size_t)bh * 1024 * 128;
  const u16* vh = va_t + (size_t)bh * 64 * 1024;
  const int s0 = qt * 128;

  if (flags) {
    if (tid < 16) mflags[tid] = flags[(b * 8 + qt) * 16 + tid];
    __syncthreads();
  } else {
    if (tid < 16) mflags[tid] = 1;
    __syncthreads();
    const int* mbase = mask + ((size_t)b * 1024 + s0) * 1024 + tid * 4;
    int ok = 1;
#pragma unroll 4
    for (int i = 0; i < 128; i++) {
      const int4 m4 = *(const int4*)(const void*)(mbase + (size_t)i * 1024);
      if (!(m4.x && m4.y && m4.z && m4.w)) ok = 0;
    }
    if (!ok) atomicAnd(&mflags[tid >> 4], 0);
    __syncthreads();
  }

  bf16x8 aq[2][4];
#pragma unroll
  for (int mi = 0; mi < 2; mi++) {
    int row = s0 + wid * 32 + mi * 16 + cl;
#pragma unroll
    for (int kk = 0; kk < 4; kk++)
      aq[mi][kk] = *(const bf16x8*)(const void*)&qh[(size_t)row * 128 + kk * 32 + gl * 8];
  }

  f32x4 acc_o[2][4];
  float l_part[2][4];
  const f32x4 vzero = {0.f, 0.f, 0.f, 0.f};
#pragma unroll
  for (int mi = 0; mi < 2; mi++) {
#pragma unroll
    for (int nj = 0; nj < 4; nj++) acc_o[mi][nj] = vzero;
#pragma unroll
    for (int r = 0; r < 4; r++) l_part[mi][r] = 0.f;
  }

  const float scale = 0.08838834764831845f;
  u16* pw = &Ps[wid * 32 * 72];

  int krow[4], kp[4], vrow[2], vp[2];
#pragma unroll
  for (int j = 0; j < 4; j++) {
    int f = (wid * 4 + j) * 64 + lane;
    krow[j] = f >> 4; kp[j] = f & 15;
  }
#pragma unroll
  for (int j = 0; j < 2; j++) {
    int f = (wid * 2 + j) * 64 + lane;
    vrow[j] = f >> 3; vp[j] = f & 7;
  }

  bf16x8 kv[4], vv[2];
  auto stageKV = [&](int kt) {
#pragma unroll
    for (int j = 0; j < 4; j++)
      kv[j] = *(const bf16x8*)(const void*)&kh[(size_t)(kt * 64 + krow[j]) * 128 + kp[j] * 8];
#pragma unroll
    for (int j = 0; j < 2; j++)
      vv[j] = *(const bf16x8*)(const void*)&vh[(size_t)vrow[j] * 1024 + kt * 64 + vp[j] * 8];
  };

  stageKV(0);

  for (int kt = 0; kt < 16; kt++) {
    __syncthreads();
#pragma unroll
    for (int j = 0; j < 4; j++)
      *(bf16x8*)(void*)&Ks[krow[j] * 136 + kp[j] * 8] = kv[j];
#pragma unroll
    for (int j = 0; j < 2; j++)
      *(bf16x8*)(void*)&Vs[vrow[j] * 72 + vp[j] * 8] = vv[j];
    __syncthreads();

    if (kt < 15) stageKV(kt + 1);

    f32x4 sc[2][4];
#pragma unroll
    for (int mi = 0; mi < 2; mi++)
#pragma unroll
      for (int nj = 0; nj < 4; nj++) sc[mi][nj] = vzero;
#pragma unroll
    for (int kk = 0; kk < 4; kk++) {
      bf16x8 bk[4];
#pragma unroll
      for (int nj = 0; nj < 4; nj++)
        bk[nj] = *(const bf16x8*)(const void*)&Ks[(nj * 16 + cl) * 136 + (kk * 4 + gl) * 8];
#pragma unroll
      for (int mi = 0; mi < 2; mi++)
#pragma unroll
        for (int nj = 0; nj < 4; nj++)
          sc[mi][nj] = __builtin_amdgcn_mfma_f32_16x16x32_bf16(aq[mi][kk], bk[nj], sc[mi][nj], 0, 0, 0);
    }

    const bool fastm = (mflags[kt] != 0);
#pragma unroll
    for (int mi = 0; mi < 2; mi++) {
#pragma unroll
      for (int nj = 0; nj < 4; nj++) {
        int key = kt * 64 + nj * 16 + cl;
#pragma unroll
        for (int r = 0; r < 4; r++) {
          int lrow = mi * 16 + gl * 4 + r;
          float sv = fminf(sc[mi][nj][r] * scale, 30.0f);
          float pv;
          if (fastm) {
            pv = __expf(sv);
          } else {
            int qrow = s0 + wid * 32 + lrow;
            int mv = mask[((size_t)b * 1024 + qrow) * 1024 + key];
            pv = (mv != 0) ? __expf(sv) : 0.0f;
          }
          l_part[mi][r] += pv;
          pw[lrow * 72 + nj * 16 + cl] = f2bf(pv);
        }
      }
    }

#pragma unroll
    for (int kk = 0; kk < 2; kk++) {
      bf16x8 ap[2], bv[4];
#pragma unroll
      for (int mi = 0; mi < 2; mi++)
        ap[mi] = *(const bf16x8*)(const void*)&pw[(mi * 16 + cl) * 72 + kk * 32 + gl * 8];
#pragma unroll
      for (int nj = 0; nj < 4; nj++)
        bv[nj] = *(const bf16x8*)(const void*)&Vs[(nj * 16 + cl) * 72 + (kk * 4 + gl) * 8];
#pragma unroll
      for (int mi = 0; mi < 2; mi++)
#pragma unroll
        for (int nj = 0; nj < 4; nj++)
          acc_o[mi][nj] = __builtin_amdgcn_mfma_f32_16x16x32_bf16(ap[mi], bv[nj], acc_o[mi][nj], 0, 0, 0);
    }
  }

#pragma unroll
  for (int mi = 0; mi < 2; mi++)
#pragma unroll
    for (int r = 0; r < 4; r++) {
      float s = l_part[mi][r];
      s += __shfl_xor(s, 1);
      s += __shfl_xor(s, 2);
      s += __shfl_xor(s, 4);
      s += __shfl_xor(s, 8);
      l_part[mi][r] = 1.0f / s;
    }

#pragma unroll
  for (int mi = 0; mi < 2; mi++)
#pragma unroll
    for (int nj = 0; nj < 4; nj++)
#pragma unroll
      for (int r = 0; r < 4; r++) {
        int srow = s0 + wid * 32 + mi * 16 + gl * 4 + r;
        int dv = nj * 16 + cl;
        float v = acc_o[mi][nj][r] * l_part[mi][r];
        x_buf[((size_t)b * 1024 + srow) * 1024 + h * 64 + dv] = f2bf(v);
      }
}

// ---------------------------------------------------------------------------
extern "C" void kernel_launch(void* const* d_in, const int* in_sizes, int n_in,
                              void* d_out, int out_size, void* d_ws, size_t ws_size,
                              hipStream_t stream) {
  (void)in_sizes; (void)n_in; (void)out_size;
  const int* mask = (const int*)d_in[5];

  char* ws = (char*)d_ws;
  u16* q_buf = (u16*)(ws);
  u16* k_buf = (u16*)(ws + ((size_t)16 << 20));
  u16* va_t  = (u16*)(ws + ((size_t)32 << 20));
  u16* x_buf = (u16*)(ws + ((size_t)40 << 20));
  u16* g_buf = (ws_size >= ((size_t)56 << 20)) ? (u16*)(ws + ((size_t)48 << 20)) : nullptr;

  // input index maps (act order: qa, qg, ka, kg, va; W order: Wqa,Wqg,Wka,Wkg,Wva,Wgate,Winfo)
  const int act_idx[5] = {2, 0, 3, 1, 4};
  const int w_idx[7] = {10, 6, 12, 8, 14, 16, 18};
  const int b_idx[7] = {11, 7, 13, 9, 15, 17, 19};

  const bool big = (ws_size >= ((size_t)112 << 20)) && (g_buf != nullptr);
  int* flags = (ws_size >= ((size_t)112 << 20) + 4096) ? (int*)(ws + ((size_t)112 << 20)) : nullptr;

  if (big) {
    // bf16 buffers: acts @56MB (5 x 8MB), W0-4 @96MB (2MB ea), Wgate @106MB (4MB), Winfo @110MB (2MB)
    u16* actb[5];
    for (int i = 0; i < 5; i++) actb[i] = (u16*)(ws + ((size_t)56 << 20) + (size_t)i * (8 << 20));
    u16* wb[7];
    for (int i = 0; i < 5; i++) wb[i] = (u16*)(ws + ((size_t)96 << 20) + (size_t)i * (2 << 20));
    wb[5] = (u16*)(ws + ((size_t)106 << 20));
    wb[6] = (u16*)(ws + ((size_t)110 << 20));

    CvtArgs C;
    for (int i = 0; i < 5; i++) {
      C.src[i] = (const float*)d_in[act_idx[i]];
      C.dst[i] = actb[i];
      C.n8[i] = (4096 * 1024) / 8;
    }
    for (int i = 0; i < 7; i++) {
      C.src[5 + i] = (const float*)d_in[w_idx[i]];
      C.dst[5 + i] = wb[i];
      C.n8[5 + i] = ((i == 5) ? (1024 * 2048) : (1024 * 1024)) / 8;
    }
    if (flags) hipLaunchKernelGGL(maskflags_kernel, dim3(512), dim3(256), 0, stream, mask, flags);
    hipLaunchKernelGGL(cvt_kernel, dim3(2048), dim3(256), 0, stream, C);

    ArgsD P;
    for (int i = 0; i < 5; i++) P.act[i] = actb[i];
    for (int i = 0; i < 7; i++) { P.W[i] = wb[i]; P.bias[i] = (const float*)d_in[b_idx[i]]; }
    P.q_buf = q_buf; P.k_buf = k_buf; P.va_t = va_t; P.x_buf = x_buf;
    P.g_buf = g_buf; P.out = (float*)d_out;

    hipLaunchKernelGGL(gemm_dma, dim3(1536), dim3(256), 0, stream, P, -1);
    hipLaunchKernelGGL(attn_kernel, dim3(512), dim3(256), 0, stream,
                       q_buf, k_buf, va_t, mask, flags, x_buf);
    hipLaunchKernelGGL(gemm_dma, dim3(256), dim3(256), 0, stream, P, 6);
  } else {
    Args P;
    for (int i = 0; i < 5; i++) P.act[i] = (const float*)d_in[act_idx[i]];
    for (int i = 0; i < 7; i++) { P.W[i] = (const float*)d_in[w_idx[i]]; P.bias[i] = (const float*)d_in[b_idx[i]]; }
    P.q_buf = q_buf; P.k_buf = k_buf; P.va_t = va_t; P.x_buf = x_buf;
    P.g_buf = g_buf; P.out = (float*)d_out;

    hipLaunchKernelGGL(gemm_kernel, dim3(1536), dim3(256), 0, stream, P, -1);
    hipLaunchKernelGGL(attn_kernel, dim3(512), dim3(256), 0, stream,
                       q_buf, k_buf, va_t, mask, (const int*)nullptr, x_buf);
    hipLaunchKernelGGL(gemm_kernel, dim3(256), dim3(256), 0, stream, P, 6);
  }
}